// Round 6
// baseline (209.260 us; speedup 1.0000x reference)
//
#include <hip/hip_runtime.h>

#define BB 8
#define NN 8192
#define NPOINT 2048
#define NSAMPLE 64
#define CIN 64
#define RADIUS 0.2f
#define R2 (RADIUS * RADIUS)

// d_out layout (flat floats, reference return order)
#define OFF_NEWXYZ 0
#define OFF_FEAT (BB * NPOINT * 3)
#define OFF_INDS (OFF_FEAT + BB * NPOINT * 128)
#define OFF_IDX (OFF_INDS + BB * NPOINT)

typedef _Float16 half8 __attribute__((ext_vector_type(8)));
typedef _Float16 half4 __attribute__((ext_vector_type(4)));
typedef __fp16 f16x2 __attribute__((ext_vector_type(2)));
typedef float floatx16 __attribute__((ext_vector_type(16)));
typedef unsigned int uint2v __attribute__((ext_vector_type(2)));

// Slice strides (halves).
#define P0 88
#define P1 72
#define X_LOC 0
#define H_LOC (64 * P0)
#define XH_WAVE (64 * P0 + 64 * P1)  // fallback kernel only
#define WT0_S 0
#define WT1_S (64 * P0)
#define WT2_S (64 * P0 + 64 * P1)

#define QPW_FB 8  // fallback: queries/wave

// d_ws layout (halves): [0, WSF16H) = fp16 features; then folded weight
// fragment tables (row-major, k-contiguous -> directly MFMA-fragment-readable)
// W0: 64 rows x 80 (cols 0-63 feat, 64-66 xyz, 67 bias=t0). W1: 64 x 64
// (t1 applied via MFMA acc-init in-kernel, R16). W2: 128 x 64.
#define WSF16H (BB * NN * CIN)        // 4194304 halves
#define WT0_OFF WSF16H
#define WT1_OFF (WT0_OFF + 64 * 80)
#define WT2_OFF (WT1_OFF + 64 * 64)
#define WS_END (WT2_OFF + 128 * 64)
#define WS_NEED ((size_t)WS_END * 2)

// ---------------------------------------------------------------------------
// prep: fp32->fp16 feature conversion (RTZ, bit-identical to the per-gather
// cvt_pkrtz) + block 0 builds BN-folded fp16 weight fragment tables. ~5us.
// ---------------------------------------------------------------------------
__global__ __launch_bounds__(256) void prep_kernel(
    const float* __restrict__ features, _Float16* __restrict__ ws16,
    const float* __restrict__ w0, const float* __restrict__ s0,
    const float* __restrict__ t0, const float* __restrict__ w1,
    const float* __restrict__ s1, const float* __restrict__ w2,
    const float* __restrict__ s2) {
  const int t = blockIdx.x * 256 + threadIdx.x;
  const float4* src = (const float4*)features;
  const float4 a = src[2 * t + 0];
  const float4 b = src[2 * t + 1];
  union {
    half8 v;
    f16x2 p[4];
  } u;
  u.p[0] = __builtin_amdgcn_cvt_pkrtz(a.x, a.y);
  u.p[1] = __builtin_amdgcn_cvt_pkrtz(a.z, a.w);
  u.p[2] = __builtin_amdgcn_cvt_pkrtz(b.x, b.y);
  u.p[3] = __builtin_amdgcn_cvt_pkrtz(b.z, b.w);
  ((half8*)ws16)[t] = u.v;
  if (blockIdx.x == 0) {  // weight fragment tables (once)
    const int tt = threadIdx.x;
    if (tt < 64) {  // wt0 row d: cols 0-63 feat, 64-66 xyz, 67 bias
      const int d = tt;
      const float sd = s0[d], td = t0[d];
      _Float16* row = ws16 + WT0_OFF + d * 80;
      for (int c = 0; c < 80; ++c) {
        float v = 0.0f;
        if (c < 64) v = w0[(3 + c) * 64 + d] * sd;
        else if (c < 67) v = w0[(c - 64) * 64 + d] * sd;
        else if (c == 67) v = td;
        row[c] = (_Float16)v;
      }
    } else if (tt < 128) {  // wt1 row d (K=64; t1 via acc-init in fused)
      const int d = tt - 64;
      const float sd = s1[d];
      _Float16* row = ws16 + WT1_OFF + d * 64;
      for (int c = 0; c < 64; ++c) row[c] = (_Float16)(w1[c * 64 + d] * sd);
    } else {  // wt2 row d2
      const int d2 = tt - 128;
      const float sd = s2[d2];
      _Float16* row = ws16 + WT2_OFF + d2 * 64;
      for (int c = 0; c < 64; ++c) row[c] = (_Float16)(w2[c * 128 + d2] * sd);
    }
  }
}

// ---- in-register layer boundary (R16, proven) ------------------------------
__device__ inline unsigned int pkru(float a, float b) {
  union {
    f16x2 p;
    unsigned int u;
  } t;
  t.p = __builtin_amdgcn_cvt_pkrtz(fmaxf(a, 0.0f), fmaxf(b, 0.0f));
  return t.u;
}
__device__ inline void build_frags(const floatx16& acc, half8& f0, half8& f1) {
  unsigned int P[4], Q[4];
#pragma unroll
  for (int rg = 0; rg < 4; ++rg) {
    P[rg] = pkru(acc[4 * rg + 0], acc[4 * rg + 1]);
    Q[rg] = pkru(acc[4 * rg + 2], acc[4 * rg + 3]);
  }
  union {
    unsigned int u[4];
    half8 h;
  } o;
  uint2v sp = __builtin_amdgcn_permlane32_swap(P[0], P[1], false, false);
  uint2v sq = __builtin_amdgcn_permlane32_swap(Q[0], Q[1], false, false);
  o.u[0] = sp.x; o.u[1] = sq.x; o.u[2] = sp.y; o.u[3] = sq.y;
  f0 = o.h;
  sp = __builtin_amdgcn_permlane32_swap(P[2], P[3], false, false);
  sq = __builtin_amdgcn_permlane32_swap(Q[2], Q[3], false, false);
  o.u[0] = sp.x; o.u[1] = sq.x; o.u[2] = sp.y; o.u[3] = sq.y;
  f1 = o.h;
}

// ---------------------------------------------------------------------------
// Fused kernel (R17): ball-query + MLP in ONE wave, one launch. The scan's
// result is one index per lane == myidx: no global idx round-trip, no second
// launch, and scan-phase VALU/memory work of some waves overlaps MFMA phases
// of others (separate pipes; waves desync via early-exit variance).
// MLP core = R16's register-handoff structure (proven): LDS only for X,
// L0->L1->L2 via cvt_pk+permlane32_swap, t1 as L1 acc-init, weights streamed
// from the d_ws table ("+s" defeats LICM). sidx overlays the X slice (512B);
// same-wave DS ops are in-order so no barrier is needed.
// ---------------------------------------------------------------------------
__global__ __launch_bounds__(64) void fused_g(
    const float* __restrict__ xyz, const _Float16* __restrict__ ws16,
    const int* __restrict__ inds, const float* __restrict__ t1,
    const float* __restrict__ t2, float* __restrict__ out) {
  __shared__ _Float16 sm[64 * P0];  // 11264 B
  const int l = threadIdx.x & 63;
  const int l31 = l & 31;
  const int h5 = l >> 5;
  const int koff = h5 * 8;

  // XCD swizzle: 8192 blocks = 8 XCDs x 1024; 1024 consecutive logical
  // blocks = one batch -> features pinned per-XCD L2.
  const int lb = (blockIdx.x & 7) * ((int)gridDim.x >> 3) + (blockIdx.x >> 3);
  const int q0 = lb * 2, q1 = q0 + 1;  // pair never straddles batch boundary
  const int b = q0 >> 11;
  const float* xb = xyz + (size_t)b * NN * 3;
  const _Float16* fb16 = ws16 + (size_t)b * NN * CIN;

  // ================= ball query: two chains, one point stream ==============
  int* sidxL = (int*)sm;  // [2][64] ints = 512 B, overlays X slice
  const int i0 = inds[q0], i1 = inds[q1];
  const float c0x = xb[i0 * 3 + 0], c0y = xb[i0 * 3 + 1], c0z = xb[i0 * 3 + 2];
  const float c1x = xb[i1 * 3 + 0], c1y = xb[i1 * 3 + 1], c1z = xb[i1 * 3 + 2];

  if (l < 2) {
    const int qq_ = l ? q1 : q0;
    const int ii = l ? i1 : i0;
    out[OFF_NEWXYZ + (size_t)qq_ * 3 + 0] = l ? c1x : c0x;
    out[OFF_NEWXYZ + (size_t)qq_ * 3 + 1] = l ? c1y : c0y;
    out[OFF_NEWXYZ + (size_t)qq_ * 3 + 2] = l ? c1z : c0z;
    out[OFF_INDS + qq_] = (float)ii;
  }

  const float qq0 = c0x * c0x + c0y * c0y + c0z * c0z;
  const float qq1 = c1x * c1x + c1y * c1y + c1z * c1z;

  int cnt0 = 0, cnt1 = 0;
  float ax[4], ay[4], az[4];
#pragma unroll
  for (int k = 0; k < 4; ++k) {
    const float* p = xb + (size_t)(k * 64 + l) * 3;
    ax[k] = p[0];
    ay[k] = p[1];
    az[k] = p[2];
  }
  for (int j0 = 0; j0 < NN; j0 += 256) {
    float bx[4] = {0}, by[4] = {0}, bz[4] = {0};
    const int jn = j0 + 256;
    if (jn < NN) {  // prefetch next chunk while ballots run on current
#pragma unroll
      for (int k = 0; k < 4; ++k) {
        const float* p = xb + (size_t)(jn + k * 64 + l) * 3;
        bx[k] = p[0];
        by[k] = p[1];
        bz[k] = p[2];
      }
    }
#pragma unroll
    for (int k = 0; k < 4; ++k) {  // k-major preserves point order
      const int j = j0 + k * 64 + l;
      const float nn_ = ax[k] * ax[k] + ay[k] * ay[k] + az[k] * az[k];
      const float dot0 = c0x * ax[k] + c0y * ay[k] + c0z * az[k];
      const float dot1 = c1x * ax[k] + c1y * ay[k] + c1z * az[k];
      const bool hit0 = (qq0 + nn_ - 2.0f * dot0) < R2;
      const bool hit1 = (qq1 + nn_ - 2.0f * dot1) < R2;
      const unsigned long long m0 = __ballot(hit0);
      const unsigned long long m1 = __ballot(hit1);
      if (hit0) {
        const int pos = cnt0 + (int)__popcll(m0 & ((1ull << l) - 1ull));
        if (pos < NSAMPLE) sidxL[pos] = j;
      }
      if (hit1) {
        const int pos = cnt1 + (int)__popcll(m1 & ((1ull << l) - 1ull));
        if (pos < NSAMPLE) sidxL[64 + pos] = j;
      }
      cnt0 += (int)__popcll(m0);
      cnt1 += (int)__popcll(m1);
    }
    if (cnt0 >= NSAMPLE && cnt1 >= NSAMPLE) break;
#pragma unroll
    for (int k = 0; k < 4; ++k) {
      ax[k] = bx[k];
      ay[k] = by[k];
      az[k] = bz[k];
    }
  }
  // Pad with first hit (center always hits itself -> cnt >= 1). Same-wave DS
  // ops are in-order: these reads see the scatter writes without a barrier.
  const int v0 = sidxL[l < cnt0 ? l : 0];
  out[OFF_IDX + (size_t)q0 * NSAMPLE + l] = (float)v0;
  const int v1 = sidxL[64 + (l < cnt1 ? l : 0)];
  out[OFF_IDX + (size_t)q1 * NSAMPLE + l] = (float)v1;

  // deep prefetch: both queries' neighbor xyz (consumed in stage-X)
  const float pp0x = xb[v0 * 3 + 0], pp0y = xb[v0 * 3 + 1],
              pp0z = xb[v0 * 3 + 2];
  const float pp1x = xb[v1 * 3 + 0], pp1y = xb[v1 * 3 + 1],
              pp1z = xb[v1 * 3 + 2];

  // ================= MLP (R16 register-handoff core) =======================
  float t2v[4];
#pragma unroll
  for (int ct = 0; ct < 4; ++ct) t2v[ct] = t2[ct * 32 + l31];
  // t1 acc-init table: t1f[nt][i] = t1[nt*32 + 8*(i>>2) + 4*h5 + (i&3)]
  float t1f[2][16];
#pragma unroll
  for (int nt = 0; nt < 2; ++nt)
#pragma unroll
    for (int rg = 0; rg < 4; ++rg) {
      const float4 tq = *(const float4*)(t1 + nt * 32 + 8 * rg + 4 * h5);
      t1f[nt][4 * rg + 0] = tq.x;
      t1f[nt][4 * rg + 1] = tq.y;
      t1f[nt][4 * rg + 2] = tq.z;
      t1f[nt][4 * rg + 3] = tq.w;
    }

  _Float16* xbuf = sm;
  {  // zero K-pad halves 72..79 (AFTER sidx reads: overlays the scan buffer)
    half8 z = {};
    *(half8*)&xbuf[l * P0 + 72] = z;
  }

  unsigned long long wbu = (unsigned long long)(ws16 + WT0_OFF);
  int myidx = v0;
  float cx = c0x, cy = c0y, cz = c0z;
  float ppx = pp0x, ppy = pp0y, ppz = pp0z;

#pragma unroll 1
  for (int qi = 0; qi < 2; ++qi) {
    const int q = q0 + qi;
    asm volatile("" : "+s"(wbu));  // opaque base: force per-query reload
    const _Float16* wt0 = (const _Float16*)wbu;
    const _Float16* wt1q = wt0 + 64 * 80;
    const _Float16* wt2q = wt0 + 64 * 80 + 64 * 64;

    // ---- fp16 grouped gather: 8 lanes share one 128B row ----
    half8 gh[8];
#pragma unroll
    for (int i = 0; i < 8; ++i) {
      const int r = (l >> 3) + 8 * i;
      const int sidx = __shfl(myidx, r, 64);
      gh[i] = *(const half8*)(fb16 + (size_t)sidx * CIN + (l & 7) * 8);
    }
    // W0 fragments (consumed by L0; latency hidden under gather-wait+stage)
    half8 b0w[2][5];
#pragma unroll
    for (int nt = 0; nt < 2; ++nt)
#pragma unroll
      for (int ks = 0; ks < 5; ++ks)
        b0w[nt][ks] =
            *(const half8*)&wt0[(nt * 32 + l31) * 80 + ks * 16 + koff];

    // ---- stage X into the slice ----
#pragma unroll
    for (int i = 0; i < 8; ++i) {
      const int r = (l >> 3) + 8 * i;
      *(half8*)&xbuf[r * P0 + (l & 7) * 8] = gh[i];
    }
    {
      union {
        half8 v;
        f16x2 p[4];
      } xv;
      xv.p[0] =
          __builtin_amdgcn_cvt_pkrtz((ppx - cx) * 5.0f, (ppy - cy) * 5.0f);
      xv.p[1] = __builtin_amdgcn_cvt_pkrtz((ppz - cz) * 5.0f, 1.0f);  // bias
      xv.p[2] = __builtin_amdgcn_cvt_pkrtz(0.0f, 0.0f);
      xv.p[3] = __builtin_amdgcn_cvt_pkrtz(0.0f, 0.0f);
      *(half8*)&xbuf[l * P0 + 64] = xv.v;
    }

    // ---- L0 (swapped): D[d][s]; epilogue builds L1 fragments in-register ----
    half8 xa1[2][4];  // H0 fragments: [st][ks], k 0..63
    {
      half8 xa[2][5];
#pragma unroll
      for (int st = 0; st < 2; ++st)
#pragma unroll
        for (int ks = 0; ks < 5; ++ks)
          xa[st][ks] =
              *(const half8*)&xbuf[(st * 32 + l31) * P0 + ks * 16 + koff];
#pragma unroll
      for (int nt = 0; nt < 2; ++nt)
#pragma unroll
        for (int st = 0; st < 2; ++st) {
          floatx16 acc;
#pragma unroll
          for (int i = 0; i < 16; ++i) acc[i] = 0.0f;
#pragma unroll
          for (int ks = 0; ks < 5; ++ks)
            acc = __builtin_amdgcn_mfma_f32_32x32x16_f16(b0w[nt][ks],
                                                         xa[st][ks], acc,
                                                         0, 0, 0);
          build_frags(acc, xa1[st][2 * nt], xa1[st][2 * nt + 1]);
        }
    }

    // ---- L1 (swapped, K=64, bias = acc init): in-register in and out ----
    half8 h1a[2][4];  // H1 fragments: [st][ks]
    {
      half8 b1w[2][4];
#pragma unroll
      for (int nt = 0; nt < 2; ++nt)
#pragma unroll
        for (int ks = 0; ks < 4; ++ks)
          b1w[nt][ks] =
              *(const half8*)&wt1q[(nt * 32 + l31) * 64 + ks * 16 + koff];
#pragma unroll
      for (int nt = 0; nt < 2; ++nt)
#pragma unroll
        for (int st = 0; st < 2; ++st) {
          floatx16 acc;
#pragma unroll
          for (int i = 0; i < 16; ++i) acc[i] = t1f[nt][i];
#pragma unroll
          for (int ks = 0; ks < 4; ++ks)
            acc = __builtin_amdgcn_mfma_f32_32x32x16_f16(b1w[nt][ks],
                                                         xa1[st][ks], acc,
                                                         0, 0, 0);
          build_frags(acc, h1a[st][2 * nt], h1a[st][2 * nt + 1]);
        }
    }

    // ---- L2 (unswapped): Y = H1 @ W2' from registers, fused maxpool ----
    {
      half8 b2c[4], b2n[4];
#pragma unroll
      for (int ks = 0; ks < 4; ++ks)
        b2c[ks] = *(const half8*)&wt2q[l31 * 64 + ks * 16 + koff];
#pragma unroll
      for (int ct = 0; ct < 4; ++ct) {
        if (ct < 3) {
#pragma unroll
          for (int ks = 0; ks < 4; ++ks)
            b2n[ks] = *(const half8*)&wt2q[((ct + 1) * 32 + l31) * 64 +
                                           ks * 16 + koff];
        }
        floatx16 aA, aB;
#pragma unroll
        for (int i = 0; i < 16; ++i) {
          aA[i] = 0.0f;
          aB[i] = 0.0f;
        }
#pragma unroll
        for (int ks = 0; ks < 4; ++ks) {
          aA = __builtin_amdgcn_mfma_f32_32x32x16_f16(h1a[0][ks], b2c[ks],
                                                      aA, 0, 0, 0);
          aB = __builtin_amdgcn_mfma_f32_32x32x16_f16(h1a[1][ks], b2c[ks],
                                                      aB, 0, 0, 0);
        }
        float m = fmaxf(aA[0], aB[0]);
#pragma unroll
        for (int i = 1; i < 16; ++i) m = fmaxf(m, fmaxf(aA[i], aB[i]));
        float v = fmaxf(m + t2v[ct], 0.0f);  // relu(max+t) == max(relu(+t))
        v = fmaxf(v, __shfl_xor(v, 32, 64));  // merge complementary halves
        if (l < 32) out[OFF_FEAT + (size_t)q * 128 + ct * 32 + l] = v;
#pragma unroll
        for (int ks = 0; ks < 4; ++ks) b2c[ks] = b2n[ks];
      }
    }

    // ---- rotate to second query (values already in registers) ----
    myidx = v1;
    cx = c1x; cy = c1y; cz = c1z;
    ppx = pp1x; ppy = pp1y; ppz = pp1z;
  }
}

// ---------------------------------------------------------------------------
// Fallback path (ws too small): original ballq + fp32-gather MLP.
// ---------------------------------------------------------------------------
__global__ __launch_bounds__(256) void ballq_kernel(
    const float* __restrict__ xyz, const int* __restrict__ inds,
    float* __restrict__ out) {
  __shared__ int sidx[4][2][NSAMPLE];
  const int wave = (blockIdx.x * 256 + threadIdx.x) >> 6;
  const int lane = threadIdx.x & 63;
  const int wid = threadIdx.x >> 6;
  const int q0 = wave * 2, q1 = q0 + 1;
  const int b = q0 >> 11;

  const float* xb = xyz + (size_t)b * NN * 3;
  const int i0 = inds[q0], i1 = inds[q1];
  const float c0x = xb[i0 * 3 + 0], c0y = xb[i0 * 3 + 1], c0z = xb[i0 * 3 + 2];
  const float c1x = xb[i1 * 3 + 0], c1y = xb[i1 * 3 + 1], c1z = xb[i1 * 3 + 2];

  if (lane < 2) {
    const int qq_ = lane ? q1 : q0;
    const int ii = lane ? i1 : i0;
    out[OFF_NEWXYZ + (size_t)qq_ * 3 + 0] = lane ? c1x : c0x;
    out[OFF_NEWXYZ + (size_t)qq_ * 3 + 1] = lane ? c1y : c0y;
    out[OFF_NEWXYZ + (size_t)qq_ * 3 + 2] = lane ? c1z : c0z;
    out[OFF_INDS + qq_] = (float)ii;
  }

  const float qq0 = c0x * c0x + c0y * c0y + c0z * c0z;
  const float qq1 = c1x * c1x + c1y * c1y + c1z * c1z;

  int cnt0 = 0, cnt1 = 0;
  float ax[4], ay[4], az[4];
#pragma unroll
  for (int k = 0; k < 4; ++k) {
    const float* p = xb + (size_t)(k * 64 + lane) * 3;
    ax[k] = p[0];
    ay[k] = p[1];
    az[k] = p[2];
  }
  for (int j0 = 0; j0 < NN; j0 += 256) {
    float bx[4] = {0}, by[4] = {0}, bz[4] = {0};
    const int jn = j0 + 256;
    if (jn < NN) {
#pragma unroll
      for (int k = 0; k < 4; ++k) {
        const float* p = xb + (size_t)(jn + k * 64 + lane) * 3;
        bx[k] = p[0];
        by[k] = p[1];
        bz[k] = p[2];
      }
    }
#pragma unroll
    for (int k = 0; k < 4; ++k) {
      const int j = j0 + k * 64 + lane;
      const float nn_ = ax[k] * ax[k] + ay[k] * ay[k] + az[k] * az[k];
      const float dot0 = c0x * ax[k] + c0y * ay[k] + c0z * az[k];
      const float dot1 = c1x * ax[k] + c1y * ay[k] + c1z * az[k];
      const bool hit0 = (qq0 + nn_ - 2.0f * dot0) < R2;
      const bool hit1 = (qq1 + nn_ - 2.0f * dot1) < R2;
      const unsigned long long m0 = __ballot(hit0);
      const unsigned long long m1 = __ballot(hit1);
      if (hit0) {
        const int pos = cnt0 + (int)__popcll(m0 & ((1ull << lane) - 1ull));
        if (pos < NSAMPLE) sidx[wid][0][pos] = j;
      }
      if (hit1) {
        const int pos = cnt1 + (int)__popcll(m1 & ((1ull << lane) - 1ull));
        if (pos < NSAMPLE) sidx[wid][1][pos] = j;
      }
      cnt0 += (int)__popcll(m0);
      cnt1 += (int)__popcll(m1);
    }
    if (cnt0 >= NSAMPLE && cnt1 >= NSAMPLE) break;
#pragma unroll
    for (int k = 0; k < 4; ++k) {
      ax[k] = bx[k];
      ay[k] = by[k];
      az[k] = bz[k];
    }
  }
  const int v0 = sidx[wid][0][lane < cnt0 ? lane : 0];
  out[OFF_IDX + (size_t)q0 * NSAMPLE + lane] = (float)v0;
  const int v1 = sidx[wid][1][lane < cnt1 ? lane : 0];
  out[OFF_IDX + (size_t)q1 * NSAMPLE + lane] = (float)v1;
}

__global__ __launch_bounds__(128, 2) void mlp_fb(
    const float* __restrict__ xyz, const float* __restrict__ features,
    const int* __restrict__ inds,
    const float* __restrict__ w0, const float* __restrict__ s0,
    const float* __restrict__ t0, const float* __restrict__ w1,
    const float* __restrict__ s1, const float* __restrict__ t1,
    const float* __restrict__ w2, const float* __restrict__ s2,
    const float* __restrict__ t2, float* __restrict__ out) {
  __shared__ _Float16 sm[2 * XH_WAVE];
  const int tid = threadIdx.x;
  const int w = tid >> 6;
  const int l = tid & 63;
  const int l31 = l & 31;
  const int h5 = l >> 5;
  const int koff = h5 * 8;

  {
    const int d = tid >> 1, hf = tid & 1;
    const float sd0 = s0[d], td0 = t0[d], sd1 = s1[d];
#pragma unroll
    for (int j = 0; j < 44; ++j) {
      const int c = hf * 44 + j;
      float v = 0.0f;
      if (c < 64) v = w0[(3 + c) * 64 + d] * sd0;
      else if (c < 67) v = w0[(c - 64) * 64 + d] * sd0;
      else if (c == 67) v = td0;
      sm[WT0_S + d * P0 + c] = (_Float16)v;
    }
#pragma unroll
    for (int j = 0; j < 32; ++j) {
      const int c = hf * 32 + j;
      sm[WT1_S + d * P1 + c] = (_Float16)(w1[c * 64 + d] * sd1);
    }
    const int ch = tid;
    const float sch = s2[ch];
#pragma unroll
    for (int c = 0; c < 64; ++c)
      sm[WT2_S + ch * P1 + c] = (_Float16)(w2[c * 128 + ch] * sch);
  }
  __syncthreads();

  half8 b0f[2][5], b1f[2][4], b2f[4][4];
#pragma unroll
  for (int nt = 0; nt < 2; ++nt)
#pragma unroll
    for (int ks = 0; ks < 5; ++ks)
      b0f[nt][ks] =
          *(const half8*)&sm[WT0_S + (nt * 32 + l31) * P0 + ks * 16 + koff];
#pragma unroll
  for (int nt = 0; nt < 2; ++nt)
#pragma unroll
    for (int ks = 0; ks < 4; ++ks)
      b1f[nt][ks] =
          *(const half8*)&sm[WT1_S + (nt * 32 + l31) * P1 + ks * 16 + koff];
#pragma unroll
  for (int ct = 0; ct < 4; ++ct)
#pragma unroll
    for (int ks = 0; ks < 4; ++ks)
      b2f[ct][ks] =
          *(const half8*)&sm[WT2_S + (ct * 32 + l31) * P1 + ks * 16 + koff];
  const float t1v0 = t1[l31];
  const float t1v1 = t1[32 + l31];
  float t2v[4];
#pragma unroll
  for (int ct = 0; ct < 4; ++ct) t2v[ct] = t2[ct * 32 + l31];
  __syncthreads();

  _Float16* xbuf = sm + w * XH_WAVE + X_LOC;
  _Float16* hbuf = sm + w * XH_WAVE + H_LOC;
  {
    half8 z = {};
    *(half8*)&xbuf[l * P0 + 72] = z;
  }

  const int lb = (blockIdx.x & 7) * ((int)gridDim.x >> 3) + (blockIdx.x >> 3);
  const int wq0 = (lb * 2 + w) * QPW_FB;
  const int b = wq0 >> 11;
  const float* xb = xyz + (size_t)b * NN * 3;
  const float* fbase = features + (size_t)b * NN * CIN;

  int myidx = (int)out[OFF_IDX + (size_t)wq0 * NSAMPLE + l];
  int indv = inds[wq0];
  float cx = xb[indv * 3 + 0], cy = xb[indv * 3 + 1], cz = xb[indv * 3 + 2];
  float ppx = xb[myidx * 3 + 0], ppy = xb[myidx * 3 + 1],
        ppz = xb[myidx * 3 + 2];

#pragma unroll 1
  for (int qi = 0; qi < QPW_FB; ++qi) {
    const int q = wq0 + qi;
    const int nq = (qi + 1 < QPW_FB) ? q + 1 : q;

    float4 g[16];
#pragma unroll
    for (int i = 0; i < 16; ++i) {
      const int s = (l >> 2) + 16 * (i & 3);
      const int c = (l & 3) + 4 * (i >> 2);
      const int sidx = __shfl(myidx, s, 64);
      g[i] = *(const float4*)(fbase + (size_t)sidx * CIN + 4 * c);
    }
    const float fni = out[OFF_IDX + (size_t)nq * NSAMPLE + l];
    const int nindv = inds[nq];

#pragma unroll
    for (int i = 0; i < 16; ++i) {
      const int s = (l >> 2) + 16 * (i & 3);
      const int c = (l & 3) + 4 * (i >> 2);
      union {
        half4 v;
        f16x2 p[2];
      } hv;
      hv.p[0] = __builtin_amdgcn_cvt_pkrtz(g[i].x, g[i].y);
      hv.p[1] = __builtin_amdgcn_cvt_pkrtz(g[i].z, g[i].w);
      *(half4*)&xbuf[s * P0 + 4 * c] = hv.v;
    }
    {
      union {
        half8 v;
        f16x2 p[4];
      } xv;
      xv.p[0] =
          __builtin_amdgcn_cvt_pkrtz((ppx - cx) * 5.0f, (ppy - cy) * 5.0f);
      xv.p[1] = __builtin_amdgcn_cvt_pkrtz((ppz - cz) * 5.0f, 1.0f);
      xv.p[2] = __builtin_amdgcn_cvt_pkrtz(0.0f, 0.0f);
      xv.p[3] = __builtin_amdgcn_cvt_pkrtz(0.0f, 0.0f);
      *(half8*)&xbuf[l * P0 + 64] = xv.v;
    }

    {
      half8 xa[2][5];
#pragma unroll
      for (int st = 0; st < 2; ++st)
#pragma unroll
        for (int ks = 0; ks < 5; ++ks)
          xa[st][ks] =
              *(const half8*)&xbuf[(st * 32 + l31) * P0 + ks * 16 + koff];
#pragma unroll
      for (int nt = 0; nt < 2; ++nt)
#pragma unroll
        for (int st = 0; st < 2; ++st) {
          floatx16 acc;
#pragma unroll
          for (int i = 0; i < 16; ++i) acc[i] = 0.0f;
#pragma unroll
          for (int ks = 0; ks < 5; ++ks)
            acc = __builtin_amdgcn_mfma_f32_32x32x16_f16(xa[st][ks],
                                                         b0f[nt][ks], acc,
                                                         0, 0, 0);
#pragma unroll
          for (int reg = 0; reg < 16; ++reg) {
            const int row = st * 32 + (reg & 3) + 8 * (reg >> 2) + 4 * h5;
            hbuf[row * P1 + nt * 32 + l31] = (_Float16)fmaxf(acc[reg], 0.0f);
          }
        }
    }

    const int nidxs = (int)fni;
    const float ncx = xb[nindv * 3 + 0];
    const float ncy = xb[nindv * 3 + 1];
    const float ncz = xb[nindv * 3 + 2];
    const float nppx = xb[nidxs * 3 + 0];
    const float nppy = xb[nidxs * 3 + 1];
    const float nppz = xb[nidxs * 3 + 2];

    {
      half8 ha[2][4];
#pragma unroll
      for (int st = 0; st < 2; ++st)
#pragma unroll
        for (int ks = 0; ks < 4; ++ks)
          ha[st][ks] =
              *(const half8*)&hbuf[(st * 32 + l31) * P1 + ks * 16 + koff];
#pragma unroll
      for (int nt = 0; nt < 2; ++nt) {
        const float tt = nt ? t1v1 : t1v0;
#pragma unroll
        for (int st = 0; st < 2; ++st) {
          floatx16 acc;
#pragma unroll
          for (int i = 0; i < 16; ++i) acc[i] = 0.0f;
#pragma unroll
          for (int ks = 0; ks < 4; ++ks)
            acc = __builtin_amdgcn_mfma_f32_32x32x16_f16(ha[st][ks],
                                                         b1f[nt][ks], acc,
                                                         0, 0, 0);
#pragma unroll
          for (int reg = 0; reg < 16; ++reg) {
            const int row = st * 32 + (reg & 3) + 8 * (reg >> 2) + 4 * h5;
            xbuf[row * P0 + nt * 32 + l31] =
                (_Float16)fmaxf(acc[reg] + tt, 0.0f);
          }
        }
      }
    }

    {
      half8 h1a[2][4];
#pragma unroll
      for (int st = 0; st < 2; ++st)
#pragma unroll
        for (int ks = 0; ks < 4; ++ks)
          h1a[st][ks] =
              *(const half8*)&xbuf[(st * 32 + l31) * P0 + ks * 16 + koff];
#pragma unroll
      for (int ct = 0; ct < 4; ++ct) {
        floatx16 aA, aB;
#pragma unroll
        for (int i = 0; i < 16; ++i) {
          aA[i] = 0.0f;
          aB[i] = 0.0f;
        }
#pragma unroll
        for (int ks = 0; ks < 4; ++ks) {
          aA = __builtin_amdgcn_mfma_f32_32x32x16_f16(h1a[0][ks], b2f[ct][ks],
                                                      aA, 0, 0, 0);
          aB = __builtin_amdgcn_mfma_f32_32x32x16_f16(h1a[1][ks], b2f[ct][ks],
                                                      aB, 0, 0, 0);
        }
        float m = fmaxf(aA[0], aB[0]);
#pragma unroll
        for (int i = 1; i < 16; ++i) m = fmaxf(m, fmaxf(aA[i], aB[i]));
        float v = fmaxf(m + t2v[ct], 0.0f);
        v = fmaxf(v, __shfl_xor(v, 32, 64));
        if (l < 32) out[OFF_FEAT + (size_t)q * 128 + ct * 32 + l] = v;
      }
    }

    myidx = nidxs;
    cx = ncx; cy = ncy; cz = ncz;
    ppx = nppx; ppy = nppy; ppz = nppz;
  }
}

extern "C" void kernel_launch(void* const* d_in, const int* in_sizes, int n_in,
                              void* d_out, int out_size, void* d_ws,
                              size_t ws_size, hipStream_t stream) {
  const float* xyz = (const float*)d_in[0];
  const float* features = (const float*)d_in[1];
  const int* inds = (const int*)d_in[2];
  const float* w0 = (const float*)d_in[3];
  const float* s0 = (const float*)d_in[4];
  const float* t0 = (const float*)d_in[5];
  const float* w1 = (const float*)d_in[6];
  const float* s1 = (const float*)d_in[7];
  const float* t1 = (const float*)d_in[8];
  const float* w2 = (const float*)d_in[9];
  const float* s2 = (const float*)d_in[10];
  const float* t2 = (const float*)d_in[11];
  float* out = (float*)d_out;

  _Float16* ws16 = (ws_size >= WS_NEED) ? (_Float16*)d_ws : nullptr;

  const int nquery = BB * NPOINT;  // 16384
  if (ws16) {
    prep_kernel<<<2048, 256, 0, stream>>>(features, ws16, w0, s0, t0, w1, s1,
                                          w2, s2);
    // one wave per block: ballq for 2 queries + their MLP, fused
    fused_g<<<nquery / 2, 64, 0, stream>>>(xyz, ws16, inds, t1, t2, out);
  } else {
    ballq_kernel<<<nquery / 8, 256, 0, stream>>>(xyz, inds, out);
    mlp_fb<<<nquery / (2 * QPW_FB), 128, 0, stream>>>(
        xyz, features, inds, w0, s0, t0, w1, s1, t1, w2, s2, t2, out);
  }
}

// Round 7
// 175.009 us; speedup vs baseline: 1.1957x; 1.1957x over previous
//
#include <hip/hip_runtime.h>

#define BB 8
#define NN 8192
#define NPOINT 2048
#define NSAMPLE 64
#define CIN 64
#define RADIUS 0.2f
#define R2 (RADIUS * RADIUS)

// d_out layout (flat floats, reference return order)
#define OFF_NEWXYZ 0
#define OFF_FEAT (BB * NPOINT * 3)
#define OFF_INDS (OFF_FEAT + BB * NPOINT * 128)
#define OFF_IDX (OFF_INDS + BB * NPOINT)

typedef _Float16 half8 __attribute__((ext_vector_type(8)));
typedef _Float16 half4 __attribute__((ext_vector_type(4)));
typedef __fp16 f16x2 __attribute__((ext_vector_type(2)));
typedef float floatx16 __attribute__((ext_vector_type(16)));
typedef unsigned int uint2v __attribute__((ext_vector_type(2)));

// LDS weight-table strides (halves). W0: 64x88 (K=80 used). W1: 64x88 (K=80:
// col 67 = t1 bias channel). W2: 128x72 (K=64 used).
#define P0 88
#define P1 72
#define WT0_S 0
#define WT1_S (64 * P0)              // 5632
#define WT2_S (WT1_S + 64 * P0)      // 11264
#define SM_H (WT2_S + 128 * P1)      // 20480 halves = 40960 B
// Per-wave X slice (reuses the weight region after hoist): 64 x P0 halves.
#define XSL (64 * P0)                // 5632 halves per wave

#define QPW 8  // queries per wave -> 1024 blocks = 4 blocks/CU (LDS+VGPR)

// ---------------------------------------------------------------------------
// Kernel 1: ball query (R11-proven structure, untouched). Two queries per
// wave share one point stream; ballot-compaction into LDS; coalesced store.
// ---------------------------------------------------------------------------
__global__ __launch_bounds__(256) void ballq_kernel(
    const float* __restrict__ xyz, const int* __restrict__ inds,
    float* __restrict__ out) {
  __shared__ int sidx[4][2][NSAMPLE];  // 2 KB: 4 waves x 2 queries
  const int wave = (blockIdx.x * 256 + threadIdx.x) >> 6;
  const int lane = threadIdx.x & 63;
  const int wid = threadIdx.x >> 6;
  const int q0 = wave * 2, q1 = q0 + 1;
  const int b = q0 >> 11;  // NPOINT = 2048; pair shares batch

  const float* xb = xyz + (size_t)b * NN * 3;
  const int i0 = inds[q0], i1 = inds[q1];
  const float c0x = xb[i0 * 3 + 0], c0y = xb[i0 * 3 + 1], c0z = xb[i0 * 3 + 2];
  const float c1x = xb[i1 * 3 + 0], c1y = xb[i1 * 3 + 1], c1z = xb[i1 * 3 + 2];

  if (lane < 2) {
    const int qq_ = lane ? q1 : q0;
    const int ii = lane ? i1 : i0;
    out[OFF_NEWXYZ + (size_t)qq_ * 3 + 0] = lane ? c1x : c0x;
    out[OFF_NEWXYZ + (size_t)qq_ * 3 + 1] = lane ? c1y : c0y;
    out[OFF_NEWXYZ + (size_t)qq_ * 3 + 2] = lane ? c1z : c0z;
    out[OFF_INDS + qq_] = (float)ii;
  }

  const float qq0 = c0x * c0x + c0y * c0y + c0z * c0z;
  const float qq1 = c1x * c1x + c1y * c1y + c1z * c1z;

  int cnt0 = 0, cnt1 = 0;
  float ax[4], ay[4], az[4];
#pragma unroll
  for (int k = 0; k < 4; ++k) {
    const float* p = xb + (size_t)(k * 64 + lane) * 3;
    ax[k] = p[0];
    ay[k] = p[1];
    az[k] = p[2];
  }
  for (int j0 = 0; j0 < NN; j0 += 256) {
    float bx[4] = {0}, by[4] = {0}, bz[4] = {0};
    const int jn = j0 + 256;
    if (jn < NN) {  // prefetch next chunk while ballots run on current
#pragma unroll
      for (int k = 0; k < 4; ++k) {
        const float* p = xb + (size_t)(jn + k * 64 + lane) * 3;
        bx[k] = p[0];
        by[k] = p[1];
        bz[k] = p[2];
      }
    }
#pragma unroll
    for (int k = 0; k < 4; ++k) {  // k-major preserves point order
      const int j = j0 + k * 64 + lane;
      const float nn_ = ax[k] * ax[k] + ay[k] * ay[k] + az[k] * az[k];
      const float dot0 = c0x * ax[k] + c0y * ay[k] + c0z * az[k];
      const float dot1 = c1x * ax[k] + c1y * ay[k] + c1z * az[k];
      const bool hit0 = (qq0 + nn_ - 2.0f * dot0) < R2;
      const bool hit1 = (qq1 + nn_ - 2.0f * dot1) < R2;
      const unsigned long long m0 = __ballot(hit0);
      const unsigned long long m1 = __ballot(hit1);
      if (hit0) {
        const int pos = cnt0 + (int)__popcll(m0 & ((1ull << lane) - 1ull));
        if (pos < NSAMPLE) sidx[wid][0][pos] = j;
      }
      if (hit1) {
        const int pos = cnt1 + (int)__popcll(m1 & ((1ull << lane) - 1ull));
        if (pos < NSAMPLE) sidx[wid][1][pos] = j;
      }
      cnt0 += (int)__popcll(m0);
      cnt1 += (int)__popcll(m1);
    }
    if (cnt0 >= NSAMPLE && cnt1 >= NSAMPLE) break;
#pragma unroll
    for (int k = 0; k < 4; ++k) {
      ax[k] = bx[k];
      ay[k] = by[k];
      az[k] = bz[k];
    }
  }
  // Pad with first hit (center always hits itself -> cnt >= 1). Same-wave DS
  // ops are in-order: reads below see the scatter writes without a barrier.
  const int v0 = sidx[wid][0][lane < cnt0 ? lane : 0];
  out[OFF_IDX + (size_t)q0 * NSAMPLE + lane] = (float)v0;
  const int v1 = sidx[wid][1][lane < cnt1 ? lane : 0];
  out[OFF_IDX + (size_t)q1 * NSAMPLE + lane] = (float)v1;
}

// ---- in-register layer boundary (R16-verified) ------------------------------
// Swapped MFMA output: lane (l31,h5) holds D[d][s=st*32+l31], d = nt*32 +
// 8*rg + 4*h5 + j. Next layer's fragment needs H[s=own col][k]: one
// permlane32_swap per reg-pair delivers both lane halves uniformly.
__device__ inline unsigned int pkru(float a, float b) {
  union {
    f16x2 p;
    unsigned int u;
  } t;
  t.p = __builtin_amdgcn_cvt_pkrtz(fmaxf(a, 0.0f), fmaxf(b, 0.0f));
  return t.u;
}
__device__ inline void build_frags(const floatx16& acc, half8& f0, half8& f1) {
  unsigned int P[4], Q[4];
#pragma unroll
  for (int rg = 0; rg < 4; ++rg) {
    P[rg] = pkru(acc[4 * rg + 0], acc[4 * rg + 1]);
    Q[rg] = pkru(acc[4 * rg + 2], acc[4 * rg + 3]);
  }
  union {
    unsigned int u[4];
    half8 h;
  } o;
  uint2v sp = __builtin_amdgcn_permlane32_swap(P[0], P[1], false, false);
  uint2v sq = __builtin_amdgcn_permlane32_swap(Q[0], Q[1], false, false);
  o.u[0] = sp.x; o.u[1] = sq.x; o.u[2] = sp.y; o.u[3] = sq.y;
  f0 = o.h;
  sp = __builtin_amdgcn_permlane32_swap(P[2], P[3], false, false);
  sq = __builtin_amdgcn_permlane32_swap(Q[2], Q[3], false, false);
  o.u[0] = sp.x; o.u[1] = sq.x; o.u[2] = sp.y; o.u[3] = sq.y;
  f1 = o.h;
}

// ---------------------------------------------------------------------------
// Kernel 2 (R18): R0's best-measured base (2-wave blocks, QPW=8, LDS-staged ->
// REGISTER-HOISTED weights, fp32 grouped gather, next-query prefetch) with the
// R16-verified in-register layer handoff replacing all inter-layer LDS
// round-trips (was 128 ds_write_b16 + 20 ds_read_b128 + 1.1M bank conflicts
// per query). t1 folds into W1's K=80 bias channel, paired with a constant
// register fragment (k=67 -> 1.0) — no t1 adds, no t1 register table.
// Barrier-free main loop; LDS holds only the X tile per wave.
// ---------------------------------------------------------------------------
__global__ __launch_bounds__(128, 2) void mlp_r(
    const float* __restrict__ xyz, const float* __restrict__ features,
    const int* __restrict__ inds,
    const float* __restrict__ w0, const float* __restrict__ s0,
    const float* __restrict__ t0, const float* __restrict__ w1,
    const float* __restrict__ s1, const float* __restrict__ t1,
    const float* __restrict__ w2, const float* __restrict__ s2,
    const float* __restrict__ t2, float* __restrict__ out) {
  __shared__ _Float16 sm[SM_H];  // 40960 B -> 4 blocks/CU, 8 waves/CU
  const int tid = threadIdx.x;
  const int w = tid >> 6;
  const int l = tid & 63;
  const int l31 = l & 31;
  const int h5 = l >> 5;
  const int koff = h5 * 8;

  // ---- stage folded weights into fragment-layout LDS (block-wide, once) ----
  {
    const int d = tid >> 1, hf = tid & 1;
    const float sd0 = s0[d], td0 = t0[d], sd1 = s1[d], td1 = t1[d];
#pragma unroll
    for (int j = 0; j < 44; ++j) {
      const int c = hf * 44 + j;
      float v = 0.0f;
      if (c < 64) v = w0[(3 + c) * 64 + d] * sd0;        // feature channels
      else if (c < 67) v = w0[(c - 64) * 64 + d] * sd0;  // xyz channels
      else if (c == 67) v = td0;                         // bias channel
      sm[WT0_S + d * P0 + c] = (_Float16)v;
      float v1 = 0.0f;
      if (c < 64) v1 = w1[c * 64 + d] * sd1;
      else if (c == 67) v1 = td1;                        // t1 bias channel
      sm[WT1_S + d * P0 + c] = (_Float16)v1;
    }
    const int ch = tid;  // 0..127
    const float sch = s2[ch];
#pragma unroll
    for (int c = 0; c < 64; ++c)
      sm[WT2_S + ch * P1 + c] = (_Float16)(w2[c * 128 + ch] * sch);
  }
  __syncthreads();

  // ---- hoist weight fragments + t2 into registers ----
  half8 b0f[2][5], b1f[2][5], b2f[4][4];
#pragma unroll
  for (int nt = 0; nt < 2; ++nt)
#pragma unroll
    for (int ks = 0; ks < 5; ++ks) {
      b0f[nt][ks] =
          *(const half8*)&sm[WT0_S + (nt * 32 + l31) * P0 + ks * 16 + koff];
      b1f[nt][ks] =
          *(const half8*)&sm[WT1_S + (nt * 32 + l31) * P0 + ks * 16 + koff];
    }
#pragma unroll
  for (int ct = 0; ct < 4; ++ct)
#pragma unroll
    for (int ks = 0; ks < 4; ++ks)
      b2f[ct][ks] =
          *(const half8*)&sm[WT2_S + (ct * 32 + l31) * P1 + ks * 16 + koff];
  float t2v[4];
#pragma unroll
  for (int ct = 0; ct < 4; ++ct) t2v[ct] = t2[ct * 32 + l31];
  __syncthreads();  // all fragment reads done before slices overwrite region

  // constant K=80 bias fragment for L1 (k = 64 + 8*h5 + j; k==67 -> 1.0)
  half8 bias_f = {};
  if (h5 == 0) bias_f[3] = (_Float16)1.0f;

  _Float16* xbuf = sm + w * XSL;
  {  // zero X K-pad halves 72..79 once (64..71 rewritten per query)
    half8 z = {};
    *(half8*)&xbuf[l * P0 + 72] = z;
  }

  // XCD swizzle: 1024 blocks = 8 XCDs x 128; 128 consecutive logical blocks
  // = one batch -> each batch's features pinned to one XCD's L2.
  const int lb = (blockIdx.x & 7) * ((int)gridDim.x >> 3) + (blockIdx.x >> 3);
  const int wq0 = (lb * 2 + w) * QPW;
  const int b = wq0 >> 11;  // all QPW queries share one batch (wq0 % 8 == 0)
  const float* xb = xyz + (size_t)b * NN * 3;
  const float* fbase = features + (size_t)b * NN * CIN;

  // ---- prologue: first query's idx / center / pp ----
  int myidx = (int)out[OFF_IDX + (size_t)wq0 * NSAMPLE + l];
  int indv = inds[wq0];
  float cx = xb[indv * 3 + 0], cy = xb[indv * 3 + 1], cz = xb[indv * 3 + 2];
  float ppx = xb[myidx * 3 + 0], ppy = xb[myidx * 3 + 1],
        ppz = xb[myidx * 3 + 2];

#pragma unroll 1
  for (int qi = 0; qi < QPW; ++qi) {
    const int q = wq0 + qi;
    const int nq = (qi + 1 < QPW) ? q + 1 : q;  // clamp: redundant reload ok

    // ---- grouped coalesced fp32 feature gather (16 lines/instr) ----
    float4 g[16];
#pragma unroll
    for (int i = 0; i < 16; ++i) {
      const int s = (l >> 2) + 16 * (i & 3);
      const int c = (l & 3) + 4 * (i >> 2);
      const int sidx = __shfl(myidx, s, 64);
      g[i] = *(const float4*)(fbase + (size_t)sidx * CIN + 4 * c);
    }
    // issue next query's idx + inds loads (consumed after L0 / at rotate)
    const float fni = out[OFF_IDX + (size_t)nq * NSAMPLE + l];
    const int nindv = inds[nq];

    // ---- stage X ----
#pragma unroll
    for (int i = 0; i < 16; ++i) {
      const int s = (l >> 2) + 16 * (i & 3);
      const int c = (l & 3) + 4 * (i >> 2);
      union {
        half4 v;
        f16x2 p[2];
      } hv;
      hv.p[0] = __builtin_amdgcn_cvt_pkrtz(g[i].x, g[i].y);
      hv.p[1] = __builtin_amdgcn_cvt_pkrtz(g[i].z, g[i].w);
      *(half4*)&xbuf[s * P0 + 4 * c] = hv.v;
    }
    {
      union {
        half8 v;
        f16x2 p[4];
      } xv;
      xv.p[0] =
          __builtin_amdgcn_cvt_pkrtz((ppx - cx) * 5.0f, (ppy - cy) * 5.0f);
      xv.p[1] = __builtin_amdgcn_cvt_pkrtz((ppz - cz) * 5.0f, 1.0f);  // bias
      xv.p[2] = __builtin_amdgcn_cvt_pkrtz(0.0f, 0.0f);
      xv.p[3] = __builtin_amdgcn_cvt_pkrtz(0.0f, 0.0f);
      *(half8*)&xbuf[l * P0 + 64] = xv.v;
    }

    // ---- L0 (swapped, K=80): D[d][s]; build L1 fragments in-register ----
    half8 xa1[2][4];  // H0 fragments: [st][ks], k 0..63
    {
      half8 xa[2][5];
#pragma unroll
      for (int st = 0; st < 2; ++st)
#pragma unroll
        for (int ks = 0; ks < 5; ++ks)
          xa[st][ks] =
              *(const half8*)&xbuf[(st * 32 + l31) * P0 + ks * 16 + koff];
#pragma unroll
      for (int nt = 0; nt < 2; ++nt)
#pragma unroll
        for (int st = 0; st < 2; ++st) {
          floatx16 acc;
#pragma unroll
          for (int i = 0; i < 16; ++i) acc[i] = 0.0f;
#pragma unroll
          for (int ks = 0; ks < 5; ++ks)
            acc = __builtin_amdgcn_mfma_f32_32x32x16_f16(b0f[nt][ks],
                                                         xa[st][ks], acc,
                                                         0, 0, 0);
          build_frags(acc, xa1[st][2 * nt], xa1[st][2 * nt + 1]);
        }
    }

    // ---- issue next query's center + pp loads (covered by L1+L2) ----
    const int nidxs = (int)fni;
    const float ncx = xb[nindv * 3 + 0];
    const float ncy = xb[nindv * 3 + 1];
    const float ncz = xb[nindv * 3 + 2];
    const float nppx = xb[nidxs * 3 + 0];
    const float nppy = xb[nidxs * 3 + 1];
    const float nppz = xb[nidxs * 3 + 2];

    // ---- L1 (swapped, K=80: t1 via bias channel + constant fragment) ----
    half8 h1a[2][4];  // H1 fragments: [st][ks]
    {
#pragma unroll
      for (int nt = 0; nt < 2; ++nt)
#pragma unroll
        for (int st = 0; st < 2; ++st) {
          floatx16 acc;
#pragma unroll
          for (int i = 0; i < 16; ++i) acc[i] = 0.0f;
#pragma unroll
          for (int ks = 0; ks < 4; ++ks)
            acc = __builtin_amdgcn_mfma_f32_32x32x16_f16(b1f[nt][ks],
                                                         xa1[st][ks], acc,
                                                         0, 0, 0);
          acc = __builtin_amdgcn_mfma_f32_32x32x16_f16(b1f[nt][4], bias_f,
                                                       acc, 0, 0, 0);
          build_frags(acc, h1a[st][2 * nt], h1a[st][2 * nt + 1]);
        }
    }

    // ---- L2 (unswapped): Y = H1 @ W2' from registers, fused maxpool ----
    {
#pragma unroll
      for (int ct = 0; ct < 4; ++ct) {
        floatx16 aA, aB;
#pragma unroll
        for (int i = 0; i < 16; ++i) {
          aA[i] = 0.0f;
          aB[i] = 0.0f;
        }
#pragma unroll
        for (int ks = 0; ks < 4; ++ks) {
          aA = __builtin_amdgcn_mfma_f32_32x32x16_f16(h1a[0][ks], b2f[ct][ks],
                                                      aA, 0, 0, 0);
          aB = __builtin_amdgcn_mfma_f32_32x32x16_f16(h1a[1][ks], b2f[ct][ks],
                                                      aB, 0, 0, 0);
        }
        float m = fmaxf(aA[0], aB[0]);
#pragma unroll
        for (int i = 1; i < 16; ++i) m = fmaxf(m, fmaxf(aA[i], aB[i]));
        float v = fmaxf(m + t2v[ct], 0.0f);  // relu(max+t) == max(relu(+t))
        v = fmaxf(v, __shfl_xor(v, 32, 64));  // merge complementary halves
        if (l < 32) out[OFF_FEAT + (size_t)q * 128 + ct * 32 + l] = v;
      }
    }

    // ---- rotate pipeline registers ----
    myidx = nidxs;
    cx = ncx; cy = ncy; cz = ncz;
    ppx = nppx; ppy = nppy; ppz = nppz;
  }
}

extern "C" void kernel_launch(void* const* d_in, const int* in_sizes, int n_in,
                              void* d_out, int out_size, void* d_ws,
                              size_t ws_size, hipStream_t stream) {
  const float* xyz = (const float*)d_in[0];
  const float* features = (const float*)d_in[1];
  const int* inds = (const int*)d_in[2];
  const float* w0 = (const float*)d_in[3];
  const float* s0 = (const float*)d_in[4];
  const float* t0 = (const float*)d_in[5];
  const float* w1 = (const float*)d_in[6];
  const float* s1 = (const float*)d_in[7];
  const float* t1 = (const float*)d_in[8];
  const float* w2 = (const float*)d_in[9];
  const float* s2 = (const float*)d_in[10];
  const float* t2 = (const float*)d_in[11];
  float* out = (float*)d_out;

  const int nquery = BB * NPOINT;  // 16384
  // ballq: 2 queries per wave -> 8192 waves -> 2048 blocks
  ballq_kernel<<<nquery / 8, 256, 0, stream>>>(xyz, inds, out);
  // mlp: 2 waves/block * QPW queries each -> 1024 blocks = 4 blocks/CU
  mlp_r<<<nquery / (2 * QPW), 128, 0, stream>>>(
      xyz, features, inds, w0, s0, t0, w1, s1, t1, w2, s2, t2, out);
}